// Round 2
// baseline (161.206 us; speedup 1.0000x reference)
//
#include <hip/hip_runtime.h>
#include <hip/hip_bf16.h>
#include <math.h>

#define B_ 16
#define C_ 64
#define N_ 4096   // 64*64 pixels
#define M_ 1024   // 32*32 pooled keys

typedef __attribute__((ext_vector_type(8))) short v8s;   // 8 bf16 (4 VGPRs)
typedef __attribute__((ext_vector_type(4))) short v4s;   // 4 bf16 (2 VGPRs)
typedef __attribute__((ext_vector_type(4))) float v4f;   // 4 fp32 acc

__device__ inline unsigned short f2bf(float f) {
    __hip_bfloat16 h = __float2bfloat16(f);
    return *(unsigned short*)&h;
}
__device__ inline unsigned pack2bf(float a, float b) {
    return (unsigned)f2bf(a) | ((unsigned)f2bf(b) << 16);
}
__device__ inline v8s cvt8(float4 a, float4 b) {
    union { v8s v; unsigned u[4]; } r;
    r.u[0] = pack2bf(a.x, a.y);
    r.u[1] = pack2bf(a.z, a.w);
    r.u[2] = pack2bf(b.x, b.y);
    r.u[3] = pack2bf(b.z, b.w);
    return r.v;
}
__device__ inline v4s cvt4(float4 a) {
    union { v4s v; unsigned u[2]; } r;
    r.u[0] = pack2bf(a.x, a.y);
    r.u[1] = pack2bf(a.z, a.w);
    return r.v;
}

// K=16 bf16 MFMA (A,B = 4 bf16/lane): A[m=l15][k=l4*4+j],
// B[k=l4*4+j][n=l15], C/D: col=l15, row=l4*4+reg (16x16-family layout).
__device__ inline v4f mfma16(v4s a, v4s b, v4f c) {
#if __has_builtin(__builtin_amdgcn_mfma_f32_16x16x16bf16_1k)
    return __builtin_amdgcn_mfma_f32_16x16x16bf16_1k(a, b, c, 0, 0, 0);
#else
    v4f d;
    asm volatile("v_mfma_f32_16x16x16_bf16 %0, %1, %2, %3\n\t"
                 "s_nop 7\n\ts_nop 7"
                 : "=&v"(d) : "v"(a), "v"(b), "v"(c));
    return d;
#endif
}

// ---------------------------------------------------------------------------
// Kernel 1 (round 6): MFMA conv, 4 waves/SIMD. Block = one row-pair, 8 waves
// of 512 threads; wave = (row, quarter-row of 16 px); grid = 16 x 32 = 512
// blocks -> 2 blocks/CU -> 4 waves/SIMD (was 2). Weights in A-frags loaded
// once. m-tiles: 0=[theta(8);phi(8)], 1=g[0..15], 2=g[16..31].
// MFMA 16x16x32 layouts (measured m89/m91): A[m=l15][k=l4*8+j],
// B[k=l4*8+j][n=l15], C/D: col(n)=l15, row(m)=l4*4+reg.
// ---------------------------------------------------------------------------
#define SP2 66   // sPool row stride (floats)

__global__ __launch_bounds__(512, 4) void conv_pool_k(
    const float* __restrict__ x,
    const float* __restrict__ Wt, const float* __restrict__ bt,
    const float* __restrict__ Wp, const float* __restrict__ bp,
    const float* __restrict__ Wg, const float* __restrict__ bg,
    unsigned short* __restrict__ thetaT,
    unsigned short* __restrict__ phiT,
    unsigned short* __restrict__ gcm)
{
    __shared__ float sPool[80 * SP2];   // 40 ch x 2 rows, 21.1 KB

    const int tid  = threadIdx.x;
    const int lane = tid & 63;
    const int wid  = tid >> 6;          // 0..7
    const int l15  = lane & 15;
    const int l4   = lane >> 4;

    const int b  = blockIdx.x >> 5;
    const int y0 = (blockIdx.x & 31) << 1;   // first of 2 image rows
    const int y  = y0 + (wid >> 2);          // this wave's row
    const int qt = wid & 3;                  // quarter-row (16 px)

    // --- A-fragments: weights, 3 m-tiles x 2 k-halves (bf16, loaded once)
    const float* row0 = (l15 < 8) ? (Wt + l15 * 64) : (Wp + (l15 - 8) * 64);
    const float* row1 = Wg + l15 * 64;
    const float* row2 = Wg + (16 + l15) * 64;
    v8s afrag[3][2];
    #pragma unroll
    for (int kh = 0; kh < 2; ++kh) {
        const int c0 = kh * 32 + l4 * 8;
        afrag[0][kh] = cvt8(*(const float4*)(row0 + c0), *(const float4*)(row0 + c0 + 4));
        afrag[1][kh] = cvt8(*(const float4*)(row1 + c0), *(const float4*)(row1 + c0 + 4));
        afrag[2][kh] = cvt8(*(const float4*)(row2 + c0), *(const float4*)(row2 + c0 + 4));
    }

    // --- accumulators init = bias (C-layout: row o = l4*4+r)
    v4f acc[3];
    #pragma unroll
    for (int r = 0; r < 4; ++r) {
        const int o = l4 * 4 + r;
        acc[0][r] = (o < 8) ? bt[o] : bp[o - 8];
        acc[1][r] = bg[o];
        acc[2][r] = bg[16 + o];
    }

    // --- main GEMM: 1 n-tile x 2 k-halves x 3 m-tiles
    const float* xb = x + (size_t)b * C_ * N_ + y * 64;
    const int n0 = qt * 16 + l15;
    #pragma unroll
    for (int kh = 0; kh < 2; ++kh) {
        const int cb = kh * 32 + l4 * 8;
        float f[8];
        #pragma unroll
        for (int j = 0; j < 8; ++j) f[j] = xb[(size_t)(cb + j) * N_ + n0];
        union { v8s v; unsigned u[4]; } bf;
        #pragma unroll
        for (int j = 0; j < 4; ++j) bf.u[j] = pack2bf(f[2*j], f[2*j+1]);
        #pragma unroll
        for (int t = 0; t < 3; ++t)
            acc[t] = __builtin_amdgcn_mfma_f32_16x16x32_bf16(
                afrag[t][kh], bf.v, acc[t], 0, 0, 0);
    }

    // --- theta: straight from C-regs (rows 0..7 of m-tile 0 = lanes l4<2)
    if (l4 < 2) {
        const int n = y * 64 + n0;
        const unsigned lo = pack2bf(acc[0][0], acc[0][1]);
        const unsigned hi = pack2bf(acc[0][2], acc[0][3]);
        *(uint2*)(thetaT + ((size_t)b * N_ + n) * 8 + l4 * 4) = make_uint2(lo, hi);
    }

    // --- stage phi/g to LDS for pooling: row = ch*2 + (row-in-pair)
    {
        const int rr = wid >> 2;
        const int px = n0;
        if (l4 >= 2) {                          // phi: ch = (l4-2)*4 + r
            #pragma unroll
            for (int r = 0; r < 4; ++r)
                sPool[(((l4 - 2) * 4 + r) * 2 + rr) * SP2 + px] = acc[0][r];
        }
        #pragma unroll
        for (int r = 0; r < 4; ++r) {
            sPool[((8  + l4 * 4 + r) * 2 + rr) * SP2 + px] = acc[1][r];
            sPool[((24 + l4 * 4 + r) * 2 + rr) * SP2 + px] = acc[2][r];
        }
    }
    __syncthreads();

    // --- 2x2 maxpool + store: 40 ch x 32 pooled px per block
    {
        const int pc  = tid & 31;          // pooled col
        const int grp = tid >> 5;          // 16 groups x 3 channels
        const int mg  = (y0 >> 1) * 32 + pc;
        #pragma unroll
        for (int i = 0; i < 3; ++i) {
            const int ch = grp * 3 + i;
            if (ch < 40) {
                const float* s0 = sPool + (ch * 2 + 0) * SP2 + pc * 2;
                const float* s1 = sPool + (ch * 2 + 1) * SP2 + pc * 2;
                const float v = fmaxf(fmaxf(s0[0], s0[1]), fmaxf(s1[0], s1[1]));
                if (ch < 8) phiT[((size_t)b * M_ + mg) * 8 + ch] = f2bf(v);
                else        gcm[((size_t)(b * 32 + ch - 8)) * M_ + mg] = f2bf(v);
            }
        }
    }
}

// ---------------------------------------------------------------------------
// Kernel 2 (round 6): barrier-free, LDS-free attention + fused conv+residual.
// S^T = mfma(A=phi[m=key], B=theta[n=q]) -> lane(q=l15,l4) holds keys l4*4+r
// = EXACTLY the B-frag of a K=16 MFMA. So exp'd scores feed the PV MFMA
// in-register (no sP round-trip, no cross-lane). Likewise the O accumulator's
// C-layout (c=l4*4+r, q=l15) IS the B-frag of the K=16 output-conv MFMA.
// g/phi frags read straight from global (L2-resident). Per wave: 16 queries,
// 64 independent 16-key chunks; 1024 blocks -> 4 waves/SIMD, no syncthreads.
// Normalization applied after PV (linear); bias via conv-MFMA C-init.
// ---------------------------------------------------------------------------
__global__ __launch_bounds__(256, 4) void attn_k(
    const float* __restrict__ x,
    const unsigned short* __restrict__ thetaT,
    const unsigned short* __restrict__ phiT,
    const unsigned short* __restrict__ gcm,
    const float* __restrict__ Wo, const float* __restrict__ bo,
    const float* __restrict__ gammap,
    float* __restrict__ out)
{
    const int tid  = threadIdx.x;
    const int lane = tid & 63;
    const int wid  = tid >> 6;
    const int l15  = lane & 15;
    const int l4   = lane >> 4;

    const int b  = blockIdx.x >> 6;
    const int qw = ((blockIdx.x & 63) << 6) + wid * 16;   // 16 queries/wave

    // theta B-frag (K=16: ch = l4*4+j, real for l4<2, zero else)
    v4s bth; { v4s z = {}; bth = z; }
    if (l4 < 2)
        bth = *(const v4s*)(thetaT + ((size_t)b * N_ + qw + l15) * 8 + l4 * 4);

    const unsigned short* phb = phiT + (size_t)b * M_ * 8;
    const unsigned short* g0  = gcm + ((size_t)(b * 32) + l15) * M_;
    const unsigned short* g1  = gcm + ((size_t)(b * 32) + 16 + l15) * M_;

    v4f accA0, accA1, accB0, accB1;
    { v4f z = {}; accA0 = z; accA1 = z; accB0 = z; accB1 = z; }
    float lsum = 0.f;
    const v4f zf = {};

    #pragma unroll 4
    for (int kk = 0; kk < 64; ++kk) {          // 64 chunks of 16 keys
        // phi A-frag: lane l15 = key, k = l4*4+j channels (real l4<2)
        v4s aph; { v4s z = {}; aph = z; }
        if (l4 < 2)
            aph = *(const v4s*)(phb + ((size_t)(kk * 16 + l15)) * 8 + l4 * 4);
        // S^T: col=q(l15), row=key(l4*4+r)
        v4f s = mfma16(aph, bth, zf);
        const float e0 = __expf(s[0]), e1 = __expf(s[1]);
        const float e2 = __expf(s[2]), e3 = __expf(s[3]);
        lsum += (e0 + e1) + (e2 + e3);
        union { v4s v; unsigned u[2]; } p;
        p.u[0] = pack2bf(e0, e1);
        p.u[1] = pack2bf(e2, e3);
        // g A-frags: A[m=c(l15)][k=key(l4*4+j)]
        const v4s ag0 = *(const v4s*)(g0 + kk * 16 + l4 * 4);
        const v4s ag1 = *(const v4s*)(g1 + kk * 16 + l4 * 4);
        if (kk & 1) {
            accB0 = mfma16(ag0, p.v, accB0);
            accB1 = mfma16(ag1, p.v, accB1);
        } else {
            accA0 = mfma16(ag0, p.v, accA0);
            accA1 = mfma16(ag1, p.v, accA1);
        }
    }
    v4f accO0 = accA0 + accB0;                 // O[c=l4*4+r][q=l15], c-tile 0
    v4f accO1 = accA1 + accB1;                 // c-tile 1 (c+16)

    // softmax denominator: sum over the 4 l4-groups sharing query l15
    float v = lsum;
    v += __shfl_xor(v, 16);
    v += __shfl_xor(v, 32);
    const float rl = 1.0f / v;

    // normalize + pack O -> B-frags of the output-conv MFMA (k = c = l4*4+j)
    v4s pO0, pO1;
    {
        union { v4s v; unsigned u[2]; } t;
        t.u[0] = pack2bf(accO0[0] * rl, accO0[1] * rl);
        t.u[1] = pack2bf(accO0[2] * rl, accO0[3] * rl);
        pO0 = t.v;
        t.u[0] = pack2bf(accO1[0] * rl, accO1[1] * rl);
        t.u[1] = pack2bf(accO1[2] * rl, accO1[3] * rl);
        pO1 = t.v;
    }

    // output conv via 8 K=16 MFMAs + residual.  D[m=oc][n=q], bias in C-init.
    const float gamma = *gammap;
    const size_t colq = qw + l15;
    #pragma unroll
    for (int mt = 0; mt < 4; ++mt) {
        const int oc0 = mt * 16 + l4 * 4;
        // Wo A-frags: A[m=oc(l15)][k=c(l4*4+j)]
        const float4 w0 = *(const float4*)(Wo + (mt * 16 + l15) * 32 + l4 * 4);
        const float4 w1 = *(const float4*)(Wo + (mt * 16 + l15) * 32 + 16 + l4 * 4);
        const v4s a0 = cvt4(w0), a1 = cvt4(w1);
        const float4 bo4 = *(const float4*)(bo + oc0);
        v4f c; c[0] = bo4.x; c[1] = bo4.y; c[2] = bo4.z; c[3] = bo4.w;
        c = mfma16(a0, pO0, c);
        c = mfma16(a1, pO1, c);
        const float* xr = x   + ((size_t)(b * 64 + oc0)) * N_ + colq;
        float*       orow = out + ((size_t)(b * 64 + oc0)) * N_ + colq;
        #pragma unroll
        for (int r = 0; r < 4; ++r)
            orow[(size_t)r * N_] = gamma * c[r] + xr[(size_t)r * N_];
    }
}

// ---------------------------------------------------------------------------
extern "C" void kernel_launch(void* const* d_in, const int* in_sizes, int n_in,
                              void* d_out, int out_size, void* d_ws, size_t ws_size,
                              hipStream_t stream) {
    const float* x  = (const float*)d_in[0];
    const float* Wt = (const float*)d_in[1];
    const float* bt = (const float*)d_in[2];
    const float* Wp = (const float*)d_in[3];
    const float* bp = (const float*)d_in[4];
    const float* Wg = (const float*)d_in[5];
    const float* bg = (const float*)d_in[6];
    const float* Wo = (const float*)d_in[7];
    const float* bo = (const float*)d_in[8];
    const float* gm = (const float*)d_in[9];
    float* out = (float*)d_out;

    // workspace (bf16): thetaT [16][4096][8] | phiT [16][1024][8] | gcm [16][32][1024]
    unsigned short* thetaT = (unsigned short*)d_ws;
    unsigned short* phiT   = thetaT + (size_t)B_ * N_ * 8;
    unsigned short* gcm    = phiT   + (size_t)B_ * M_ * 8;

    hipLaunchKernelGGL(conv_pool_k, dim3(512), dim3(512), 0, stream,
                       x, Wt, bt, Wp, bp, Wg, bg, thetaT, phiT, gcm);
    hipLaunchKernelGGL(attn_k, dim3(1024), dim3(256), 0, stream,
                       x, thetaT, phiT, gcm, Wo, bo, gm, out);
}

// Round 3
// 122.756 us; speedup vs baseline: 1.3132x; 1.3132x over previous
//
#include <hip/hip_runtime.h>
#include <hip/hip_bf16.h>
#include <math.h>

#define B_ 16
#define C_ 64
#define N_ 4096   // 64*64 pixels
#define M_ 1024   // 32*32 pooled keys

typedef __attribute__((ext_vector_type(8))) short v8s;   // 8 bf16 (4 VGPRs)
typedef __attribute__((ext_vector_type(4))) short v4s;   // 4 bf16 (2 VGPRs)
typedef __attribute__((ext_vector_type(4))) float v4f;   // 4 fp32 acc

__device__ inline unsigned short f2bf(float f) {
    __hip_bfloat16 h = __float2bfloat16(f);
    return *(unsigned short*)&h;
}
__device__ inline unsigned pack2bf(float a, float b) {
    return (unsigned)f2bf(a) | ((unsigned)f2bf(b) << 16);
}
__device__ inline v8s cvt8(float4 a, float4 b) {
    union { v8s v; unsigned u[4]; } r;
    r.u[0] = pack2bf(a.x, a.y);
    r.u[1] = pack2bf(a.z, a.w);
    r.u[2] = pack2bf(b.x, b.y);
    r.u[3] = pack2bf(b.z, b.w);
    return r.v;
}
__device__ inline v4s cvt4(float4 a) {
    union { v4s v; unsigned u[2]; } r;
    r.u[0] = pack2bf(a.x, a.y);
    r.u[1] = pack2bf(a.z, a.w);
    return r.v;
}

// K=16 bf16 MFMA: A[m=l15][k=l4*4+j], B[k=l4*4+j][n=l15],
// C/D: col=l15, row=l4*4+reg (16x16-family layout).
__device__ inline v4f mfma16(v4s a, v4s b, v4f c) {
#if __has_builtin(__builtin_amdgcn_mfma_f32_16x16x16bf16_1k)
    return __builtin_amdgcn_mfma_f32_16x16x16bf16_1k(a, b, c, 0, 0, 0);
#else
    v4f d;
    asm("v_mfma_f32_16x16x16_bf16 %0, %1, %2, %3\n\ts_nop 7\n\ts_nop 7"
        : "=&v"(d) : "v"(a), "v"(b), "v"(c));
    return d;
#endif
}

// ---------------------------------------------------------------------------
// Kernel 1 (unchanged from round 6): MFMA conv, 4 waves/SIMD.
// ---------------------------------------------------------------------------
#define SP2 66   // sPool row stride (floats)

__global__ __launch_bounds__(512, 4) void conv_pool_k(
    const float* __restrict__ x,
    const float* __restrict__ Wt, const float* __restrict__ bt,
    const float* __restrict__ Wp, const float* __restrict__ bp,
    const float* __restrict__ Wg, const float* __restrict__ bg,
    unsigned short* __restrict__ thetaT,
    unsigned short* __restrict__ phiT,
    unsigned short* __restrict__ gcm)
{
    __shared__ float sPool[80 * SP2];   // 40 ch x 2 rows, 21.1 KB

    const int tid  = threadIdx.x;
    const int lane = tid & 63;
    const int wid  = tid >> 6;          // 0..7
    const int l15  = lane & 15;
    const int l4   = lane >> 4;

    const int b  = blockIdx.x >> 5;
    const int y0 = (blockIdx.x & 31) << 1;   // first of 2 image rows
    const int y  = y0 + (wid >> 2);          // this wave's row
    const int qt = wid & 3;                  // quarter-row (16 px)

    // --- A-fragments: weights, 3 m-tiles x 2 k-halves (bf16, loaded once)
    const float* row0 = (l15 < 8) ? (Wt + l15 * 64) : (Wp + (l15 - 8) * 64);
    const float* row1 = Wg + l15 * 64;
    const float* row2 = Wg + (16 + l15) * 64;
    v8s afrag[3][2];
    #pragma unroll
    for (int kh = 0; kh < 2; ++kh) {
        const int c0 = kh * 32 + l4 * 8;
        afrag[0][kh] = cvt8(*(const float4*)(row0 + c0), *(const float4*)(row0 + c0 + 4));
        afrag[1][kh] = cvt8(*(const float4*)(row1 + c0), *(const float4*)(row1 + c0 + 4));
        afrag[2][kh] = cvt8(*(const float4*)(row2 + c0), *(const float4*)(row2 + c0 + 4));
    }

    // --- accumulators init = bias (C-layout: row o = l4*4+r)
    v4f acc[3];
    #pragma unroll
    for (int r = 0; r < 4; ++r) {
        const int o = l4 * 4 + r;
        acc[0][r] = (o < 8) ? bt[o] : bp[o - 8];
        acc[1][r] = bg[o];
        acc[2][r] = bg[16 + o];
    }

    // --- main GEMM: 1 n-tile x 2 k-halves x 3 m-tiles
    const float* xb = x + (size_t)b * C_ * N_ + y * 64;
    const int n0 = qt * 16 + l15;
    #pragma unroll
    for (int kh = 0; kh < 2; ++kh) {
        const int cb = kh * 32 + l4 * 8;
        float f[8];
        #pragma unroll
        for (int j = 0; j < 8; ++j) f[j] = xb[(size_t)(cb + j) * N_ + n0];
        union { v8s v; unsigned u[4]; } bf;
        #pragma unroll
        for (int j = 0; j < 4; ++j) bf.u[j] = pack2bf(f[2*j], f[2*j+1]);
        #pragma unroll
        for (int t = 0; t < 3; ++t)
            acc[t] = __builtin_amdgcn_mfma_f32_16x16x32_bf16(
                afrag[t][kh], bf.v, acc[t], 0, 0, 0);
    }

    // --- theta: straight from C-regs (rows 0..7 of m-tile 0 = lanes l4<2)
    if (l4 < 2) {
        const int n = y * 64 + n0;
        const unsigned lo = pack2bf(acc[0][0], acc[0][1]);
        const unsigned hi = pack2bf(acc[0][2], acc[0][3]);
        *(uint2*)(thetaT + ((size_t)b * N_ + n) * 8 + l4 * 4) = make_uint2(lo, hi);
    }

    // --- stage phi/g to LDS for pooling: row = ch*2 + (row-in-pair)
    {
        const int rr = wid >> 2;
        const int px = n0;
        if (l4 >= 2) {                          // phi: ch = (l4-2)*4 + r
            #pragma unroll
            for (int r = 0; r < 4; ++r)
                sPool[(((l4 - 2) * 4 + r) * 2 + rr) * SP2 + px] = acc[0][r];
        }
        #pragma unroll
        for (int r = 0; r < 4; ++r) {
            sPool[((8  + l4 * 4 + r) * 2 + rr) * SP2 + px] = acc[1][r];
            sPool[((24 + l4 * 4 + r) * 2 + rr) * SP2 + px] = acc[2][r];
        }
    }
    __syncthreads();

    // --- 2x2 maxpool + store: 40 ch x 32 pooled px per block
    {
        const int pc  = tid & 31;          // pooled col
        const int grp = tid >> 5;          // 16 groups x 3 channels
        const int mg  = (y0 >> 1) * 32 + pc;
        #pragma unroll
        for (int i = 0; i < 3; ++i) {
            const int ch = grp * 3 + i;
            if (ch < 40) {
                const float* s0 = sPool + (ch * 2 + 0) * SP2 + pc * 2;
                const float* s1 = sPool + (ch * 2 + 1) * SP2 + pc * 2;
                const float v = fmaxf(fmaxf(s0[0], s0[1]), fmaxf(s1[0], s1[1]));
                if (ch < 8) phiT[((size_t)b * M_ + mg) * 8 + ch] = f2bf(v);
                else        gcm[((size_t)(b * 32 + ch - 8)) * M_ + mg] = f2bf(v);
            }
        }
    }
}

// ---------------------------------------------------------------------------
// Kernel 2 (round 7): K=16 in-register attention, LDS-tiled operands with
// register-prefetch double buffering.  Round-6 failure: per-chunk GLOBAL
// loads were never batched (VGPR=28) -> 64 serial L2 round-trips/wave.
// Fix: keys in 4 tiles of 256 staged in LDS (phi 4KB + g 16.5KB per buf);
// tile t+1's global loads issue BEFORE tile t's compute (regs), ds_write +
// one barrier after (T14).  Inner loop reads are ds_read_b64 (+imm),
// fully unrolled.  phi needs no zero-pad: theta B-frag is zero for k>=8,
// so lanes l4>=2 re-read a finite phi word (broadcast, conflict-free).
// 128 q/block (2 qs streams/wave), grid 512 -> 3 blocks/CU (41KB LDS).
// ---------------------------------------------------------------------------
#define PHI_SZ (256 * 8)     // shorts per phi buffer (row = 8 shorts)
#define G_STR  264           // g row stride in shorts (byte 528: 2-way banks)
#define G_SZ   (32 * G_STR)  // shorts per g buffer

__global__ __launch_bounds__(256, 3) void attn_k(
    const float* __restrict__ x,
    const unsigned short* __restrict__ thetaT,
    const unsigned short* __restrict__ phiT,
    const unsigned short* __restrict__ gcm,
    const float* __restrict__ Wo, const float* __restrict__ bo,
    const float* __restrict__ gammap,
    float* __restrict__ out)
{
    __shared__ unsigned short phiL[2 * PHI_SZ];   // 8 KB
    __shared__ unsigned short gL[2 * G_SZ];       // 33 KB

    const int tid  = threadIdx.x;
    const int lane = tid & 63;
    const int wid  = tid >> 6;
    const int l15  = lane & 15;
    const int l4   = lane >> 4;

    const int b  = blockIdx.x >> 5;
    const int q0 = (blockIdx.x & 31) << 7;   // 128 queries per block
    const int qw = q0 + wid * 32;            // this wave's 32 queries

    // --- theta B-frags (K=16: k=ch l4*4+j, real for l4<2, zero else)
    v4s bth0, bth1;
    { v4s z = {}; bth0 = z; bth1 = z; }
    if (l4 < 2) {
        bth0 = *(const v4s*)(thetaT + ((size_t)b * N_ + qw +      l15) * 8 + l4 * 4);
        bth1 = *(const v4s*)(thetaT + ((size_t)b * N_ + qw + 16 + l15) * 8 + l4 * 4);
    }

    // --- Wo A-frags + gamma hoisted off the critical tail
    v4s wA[4][2];
    #pragma unroll
    for (int mt = 0; mt < 4; ++mt) {
        const float4 w0 = *(const float4*)(Wo + (mt * 16 + l15) * 32 + l4 * 4);
        const float4 w1 = *(const float4*)(Wo + (mt * 16 + l15) * 32 + 16 + l4 * 4);
        wA[mt][0] = cvt4(w0);
        wA[mt][1] = cvt4(w1);
    }
    const float gamma = *gammap;

    // --- staging source addresses (per thread)
    const unsigned short* phSrc = phiT + ((size_t)b * M_ + tid) * 8;
    const int grow = tid >> 3, gseg = tid & 7;
    const unsigned short* gSrc = gcm + ((size_t)(b * 32 + grow)) * M_ + gseg * 32;
    unsigned short* const gDst0 = &gL[grow * G_STR + gseg * 32];

    // --- prologue: load + write tile 0
    uint4 r_ph = *(const uint4*)phSrc;
    uint4 r_g0 = *(const uint4*)(gSrc + 0);
    uint4 r_g1 = *(const uint4*)(gSrc + 8);
    uint4 r_g2 = *(const uint4*)(gSrc + 16);
    uint4 r_g3 = *(const uint4*)(gSrc + 24);
    *(uint4*)&phiL[tid * 8] = r_ph;
    *(uint4*)&gDst0[0]  = r_g0;
    *(uint4*)&gDst0[8]  = r_g1;
    *(uint4*)&gDst0[16] = r_g2;
    *(uint4*)&gDst0[24] = r_g3;
    __syncthreads();

    v4f acc[2][2];
    #pragma unroll
    for (int qs = 0; qs < 2; ++qs)
        #pragma unroll
        for (int ct = 0; ct < 2; ++ct) { v4f z = {}; acc[qs][ct] = z; }
    float lsum[2] = {0.f, 0.f};
    const v4f zf = {};

    for (int t = 0; t < 4; ++t) {
        const unsigned short* Pb = &phiL[(t & 1) * PHI_SZ];
        const unsigned short* Gb = &gL[(t & 1) * G_SZ];
        // issue next tile's global loads BEFORE compute (latency hides here)
        if (t < 3) {
            r_ph = *(const uint4*)(phSrc + (size_t)(t + 1) * 256 * 8);
            const unsigned short* gs = gSrc + (t + 1) * 256;
            r_g0 = *(const uint4*)(gs + 0);
            r_g1 = *(const uint4*)(gs + 8);
            r_g2 = *(const uint4*)(gs + 16);
            r_g3 = *(const uint4*)(gs + 24);
        }
        // compute 16 chunks of 16 keys from LDS
        const unsigned short* pAddr = Pb + l15 * 8 + (l4 & 1) * 4;  // dup for l4>=2 (B=0 there)
        const unsigned short* gAddr = Gb + l15 * G_STR + l4 * 4;
        #pragma unroll
        for (int kk = 0; kk < 16; ++kk) {
            const v4s aph = *(const v4s*)(pAddr + kk * 128);
            const v4s ag0 = *(const v4s*)(gAddr + kk * 16);
            const v4s ag1 = *(const v4s*)(gAddr + 16 * G_STR + kk * 16);
            #pragma unroll
            for (int qs = 0; qs < 2; ++qs) {
                v4f s = mfma16(aph, qs ? bth1 : bth0, zf);
                const float e0 = __expf(s[0]), e1 = __expf(s[1]);
                const float e2 = __expf(s[2]), e3 = __expf(s[3]);
                lsum[qs] += (e0 + e1) + (e2 + e3);
                union { v4s v; unsigned u[2]; } p;
                p.u[0] = pack2bf(e0, e1);
                p.u[1] = pack2bf(e2, e3);
                acc[qs][0] = mfma16(ag0, p.v, acc[qs][0]);
                acc[qs][1] = mfma16(ag1, p.v, acc[qs][1]);
            }
        }
        // write-late: next tile into the other buffer, one barrier per tile
        if (t < 3) {
            unsigned short* Pn = &phiL[((t + 1) & 1) * PHI_SZ];
            unsigned short* Gn = &gL[((t + 1) & 1) * G_SZ];
            *(uint4*)&Pn[tid * 8] = r_ph;
            unsigned short* gd = &Gn[grow * G_STR + gseg * 32];
            *(uint4*)&gd[0]  = r_g0;
            *(uint4*)&gd[8]  = r_g1;
            *(uint4*)&gd[16] = r_g2;
            *(uint4*)&gd[24] = r_g3;
            __syncthreads();
        }
    }

    // --- epilogue per qs-stream: softmax denom, normalize, conv-MFMA, residual
    #pragma unroll
    for (int qs = 0; qs < 2; ++qs) {
        float v = lsum[qs];
        v += __shfl_xor(v, 16);
        v += __shfl_xor(v, 32);
        const float rl = 1.0f / v;

        v4s pO0, pO1;
        {
            union { v4s v; unsigned u[2]; } p;
            p.u[0] = pack2bf(acc[qs][0][0] * rl, acc[qs][0][1] * rl);
            p.u[1] = pack2bf(acc[qs][0][2] * rl, acc[qs][0][3] * rl);
            pO0 = p.v;
            p.u[0] = pack2bf(acc[qs][1][0] * rl, acc[qs][1][1] * rl);
            p.u[1] = pack2bf(acc[qs][1][2] * rl, acc[qs][1][3] * rl);
            pO1 = p.v;
        }

        const size_t colq = qw + qs * 16 + l15;
        #pragma unroll
        for (int mt = 0; mt < 4; ++mt) {
            const int oc0 = mt * 16 + l4 * 4;
            const float4 bo4 = *(const float4*)(bo + oc0);
            v4f c; c[0] = bo4.x; c[1] = bo4.y; c[2] = bo4.z; c[3] = bo4.w;
            c = mfma16(wA[mt][0], pO0, c);
            c = mfma16(wA[mt][1], pO1, c);
            const float* xr   = x   + ((size_t)(b * 64 + oc0)) * N_ + colq;
            float*       orow = out + ((size_t)(b * 64 + oc0)) * N_ + colq;
            #pragma unroll
            for (int r = 0; r < 4; ++r)
                orow[(size_t)r * N_] = gamma * c[r] + xr[(size_t)r * N_];
        }
    }
}

// ---------------------------------------------------------------------------
extern "C" void kernel_launch(void* const* d_in, const int* in_sizes, int n_in,
                              void* d_out, int out_size, void* d_ws, size_t ws_size,
                              hipStream_t stream) {
    const float* x  = (const float*)d_in[0];
    const float* Wt = (const float*)d_in[1];
    const float* bt = (const float*)d_in[2];
    const float* Wp = (const float*)d_in[3];
    const float* bp = (const float*)d_in[4];
    const float* Wg = (const float*)d_in[5];
    const float* bg = (const float*)d_in[6];
    const float* Wo = (const float*)d_in[7];
    const float* bo = (const float*)d_in[8];
    const float* gm = (const float*)d_in[9];
    float* out = (float*)d_out;

    // workspace (bf16): thetaT [16][4096][8] | phiT [16][1024][8] | gcm [16][32][1024]
    unsigned short* thetaT = (unsigned short*)d_ws;
    unsigned short* phiT   = thetaT + (size_t)B_ * N_ * 8;
    unsigned short* gcm    = phiT   + (size_t)B_ * M_ * 8;

    hipLaunchKernelGGL(conv_pool_k, dim3(512), dim3(512), 0, stream,
                       x, Wt, bt, Wp, bp, Wg, bg, thetaT, phiT, gcm);
    hipLaunchKernelGGL(attn_k, dim3(512), dim3(256), 0, stream,
                       x, thetaT, phiT, gcm, Wo, bo, gm, out);
}

// Round 4
// 108.752 us; speedup vs baseline: 1.4823x; 1.1288x over previous
//
#include <hip/hip_runtime.h>
#include <hip/hip_bf16.h>
#include <math.h>

#define B_ 16
#define C_ 64
#define N_ 4096   // 64*64 pixels
#define M_ 1024   // 32*32 pooled keys

typedef __attribute__((ext_vector_type(8))) short v8s;   // 8 bf16 (4 VGPRs)
typedef __attribute__((ext_vector_type(4))) short v4s;   // 4 bf16 (2 VGPRs)
typedef __attribute__((ext_vector_type(4))) float v4f;   // 4 fp32 acc

__device__ inline unsigned short f2bf(float f) {
    __hip_bfloat16 h = __float2bfloat16(f);
    return *(unsigned short*)&h;
}
__device__ inline unsigned pack2bf(float a, float b) {
    return (unsigned)f2bf(a) | ((unsigned)f2bf(b) << 16);
}
__device__ inline v8s cvt8(float4 a, float4 b) {
    union { v8s v; unsigned u[4]; } r;
    r.u[0] = pack2bf(a.x, a.y);
    r.u[1] = pack2bf(a.z, a.w);
    r.u[2] = pack2bf(b.x, b.y);
    r.u[3] = pack2bf(b.z, b.w);
    return r.v;
}
__device__ inline v4s cvt4(float4 a) {
    union { v4s v; unsigned u[2]; } r;
    r.u[0] = pack2bf(a.x, a.y);
    r.u[1] = pack2bf(a.z, a.w);
    return r.v;
}

// K=16 bf16 MFMA: A[m=l15][k=l4*4+j], B[k=l4*4+j][n=l15],
// C/D: col=l15, row=l4*4+reg (16x16-family layout).
__device__ inline v4f mfma16(v4s a, v4s b, v4f c) {
#if __has_builtin(__builtin_amdgcn_mfma_f32_16x16x16bf16_1k)
    return __builtin_amdgcn_mfma_f32_16x16x16bf16_1k(a, b, c, 0, 0, 0);
#else
    v4f d;
    asm("v_mfma_f32_16x16x16_bf16 %0, %1, %2, %3\n\ts_nop 7\n\ts_nop 7"
        : "=&v"(d) : "v"(a), "v"(b), "v"(c));
    return d;
#endif
}

// ---------------------------------------------------------------------------
// Kernel 1 (round 8): REVERTED to the round-1 structure (measured-inferred
// 14.7 us cheaper than the 512-thread split: weight preamble amortizes over
// 12 MFMAs/wave instead of 6).  Block = one row-pair, 4 waves of 256 thr;
// wave = (row, half-row of 32 px); grid = 16 x 32 = 512 blocks.
// ---------------------------------------------------------------------------
#define SP2 66   // sPool row stride (floats)

__global__ __launch_bounds__(256, 2) void conv_pool_k(
    const float* __restrict__ x,
    const float* __restrict__ Wt, const float* __restrict__ bt,
    const float* __restrict__ Wp, const float* __restrict__ bp,
    const float* __restrict__ Wg, const float* __restrict__ bg,
    unsigned short* __restrict__ thetaT,
    unsigned short* __restrict__ phiT,
    unsigned short* __restrict__ gcm)
{
    __shared__ float sPool[80 * SP2];   // 40 ch x 2 rows = 80 rows, 21.1 KB

    const int tid  = threadIdx.x;
    const int lane = tid & 63;
    const int wid  = tid >> 6;
    const int l15  = lane & 15;
    const int l4   = lane >> 4;

    const int b  = blockIdx.x >> 5;
    const int y0 = (blockIdx.x & 31) << 1;   // first of 2 image rows
    const int y  = y0 + (wid >> 1);          // this wave's row
    const int xh = (wid & 1) * 32;           // this wave's half-row

    // --- A-fragments: weights, 3 m-tiles x 2 k-halves (bf16, loaded once)
    const float* row0 = (l15 < 8) ? (Wt + l15 * 64) : (Wp + (l15 - 8) * 64);
    const float* row1 = Wg + l15 * 64;
    const float* row2 = Wg + (16 + l15) * 64;
    v8s afrag[3][2];
    #pragma unroll
    for (int kh = 0; kh < 2; ++kh) {
        const int c0 = kh * 32 + l4 * 8;
        afrag[0][kh] = cvt8(*(const float4*)(row0 + c0), *(const float4*)(row0 + c0 + 4));
        afrag[1][kh] = cvt8(*(const float4*)(row1 + c0), *(const float4*)(row1 + c0 + 4));
        afrag[2][kh] = cvt8(*(const float4*)(row2 + c0), *(const float4*)(row2 + c0 + 4));
    }

    // --- accumulators init = bias (C-layout: row o = l4*4+r)
    v4f acc[2][3];
    {
        float bv[3][4];
        #pragma unroll
        for (int r = 0; r < 4; ++r) {
            const int o = l4 * 4 + r;               // 0..15
            bv[0][r] = (o < 8) ? bt[o] : bp[o - 8];
            bv[1][r] = bg[o];
            bv[2][r] = bg[16 + o];
        }
        #pragma unroll
        for (int nt = 0; nt < 2; ++nt)
            #pragma unroll
            for (int t = 0; t < 3; ++t) {
                v4f a; a[0] = bv[t][0]; a[1] = bv[t][1];
                a[2] = bv[t][2]; a[3] = bv[t][3];
                acc[nt][t] = a;
            }
    }

    // --- main GEMM: 2 n-tiles x 2 k-halves x 3 m-tiles
    const float* xb = x + (size_t)b * C_ * N_ + y * 64;
    #pragma unroll
    for (int nt = 0; nt < 2; ++nt) {
        const int n0 = xh + nt * 16 + l15;
        #pragma unroll
        for (int kh = 0; kh < 2; ++kh) {
            const int cb = kh * 32 + l4 * 8;
            float f[8];
            #pragma unroll
            for (int j = 0; j < 8; ++j) f[j] = xb[(size_t)(cb + j) * N_ + n0];
            union { v8s v; unsigned u[4]; } bf;
            #pragma unroll
            for (int j = 0; j < 4; ++j) bf.u[j] = pack2bf(f[2*j], f[2*j+1]);
            #pragma unroll
            for (int t = 0; t < 3; ++t)
                acc[nt][t] = __builtin_amdgcn_mfma_f32_16x16x32_bf16(
                    afrag[t][kh], bf.v, acc[nt][t], 0, 0, 0);
        }
    }

    // --- theta: straight from C-regs (rows 0..7 of m-tile 0 = lanes l4<2)
    #pragma unroll
    for (int nt = 0; nt < 2; ++nt) {
        if (l4 < 2) {
            const int n = y * 64 + xh + nt * 16 + l15;
            const unsigned lo = pack2bf(acc[nt][0][0], acc[nt][0][1]);
            const unsigned hi = pack2bf(acc[nt][0][2], acc[nt][0][3]);
            *(uint2*)(thetaT + ((size_t)b * N_ + n) * 8 + l4 * 4) = make_uint2(lo, hi);
        }
    }

    // --- stage phi/g to LDS for pooling: row index = ch*2 + (image row in pair)
    {
        const int rr = wid >> 1;   // 0/1: which row of the pair
        #pragma unroll
        for (int nt = 0; nt < 2; ++nt) {
            const int px = xh + nt * 16 + l15;      // 0..63
            if (l4 >= 2) {                          // phi: ch = (l4-2)*4 + r
                #pragma unroll
                for (int r = 0; r < 4; ++r)
                    sPool[(((l4 - 2) * 4 + r) * 2 + rr) * SP2 + px] = acc[nt][0][r];
            }
            #pragma unroll
            for (int r = 0; r < 4; ++r) {
                sPool[((8  + l4 * 4 + r) * 2 + rr) * SP2 + px] = acc[nt][1][r];
                sPool[((24 + l4 * 4 + r) * 2 + rr) * SP2 + px] = acc[nt][2][r];
            }
        }
    }
    __syncthreads();

    // --- 2x2 maxpool + store: 40 ch x 32 pooled px per block
    {
        const int pc  = tid & 31;          // pooled col
        const int grp = tid >> 5;          // 8 groups x 5 channels
        const int mg  = (y0 >> 1) * 32 + pc;
        #pragma unroll
        for (int i = 0; i < 5; ++i) {
            const int ch = grp * 5 + i;
            const float* s0 = sPool + (ch * 2 + 0) * SP2 + pc * 2;
            const float* s1 = sPool + (ch * 2 + 1) * SP2 + pc * 2;
            const float v = fmaxf(fmaxf(s0[0], s0[1]), fmaxf(s1[0], s1[1]));
            if (ch < 8) phiT[((size_t)b * M_ + mg) * 8 + ch] = f2bf(v);
            else        gcm[((size_t)(b * 32 + ch - 8)) * M_ + mg] = f2bf(v);
        }
    }
}

// ---------------------------------------------------------------------------
// Kernel 2 (round 8): K=16 in-register attention, 4 waves/SIMD.
// Round-3 version ran grid 512 = 2 blocks/CU -> 2 waves/SIMD; the per-chunk
// dependent chain (S-MFMA -> exp -> pack -> PV-MFMA) was only 2-way hidden.
// Now: 64 q/block (16 q/wave, single stream), grid 16x64 = 1024 blocks ->
// 4 blocks/CU = 4 waves/SIMD.  Key tiles shrink to 128 (8 tiles, double-
// buffered: phi 2x2KB + g 2x8.5KB = 21.5KB LDS), register prefetch kept
// (load t+1 before compute t, ds_write + one barrier after).  Same proven
// math/fragment layouts as round 3.
// ---------------------------------------------------------------------------
#define P2_SZ  (128 * 8)      // shorts per phi buffer (row = 8 shorts)
#define G2_STR 136            // g row stride in shorts (272 B -> 2-way banks)
#define G2_SZ  (32 * G2_STR)  // shorts per g buffer

__global__ __launch_bounds__(256, 4) void attn_k(
    const float* __restrict__ x,
    const unsigned short* __restrict__ thetaT,
    const unsigned short* __restrict__ phiT,
    const unsigned short* __restrict__ gcm,
    const float* __restrict__ Wo, const float* __restrict__ bo,
    const float* __restrict__ gammap,
    float* __restrict__ out)
{
    __shared__ unsigned short phiL[2 * P2_SZ];   // 4 KB
    __shared__ unsigned short gL[2 * G2_SZ];     // 17.4 KB

    const int tid  = threadIdx.x;
    const int lane = tid & 63;
    const int wid  = tid >> 6;
    const int l15  = lane & 15;
    const int l4   = lane >> 4;

    const int b  = blockIdx.x >> 6;
    const int qw = ((blockIdx.x & 63) << 6) + wid * 16;   // 16 queries/wave

    // --- theta B-frag (K=16: k=ch l4*4+j, real for l4<2, zero else)
    v4s bth; { v4s z = {}; bth = z; }
    if (l4 < 2)
        bth = *(const v4s*)(thetaT + ((size_t)b * N_ + qw + l15) * 8 + l4 * 4);

    // --- Wo A-frags + gamma hoisted off the critical tail
    v4s wA[4][2];
    #pragma unroll
    for (int mt = 0; mt < 4; ++mt) {
        const float4 w0 = *(const float4*)(Wo + (mt * 16 + l15) * 32 + l4 * 4);
        const float4 w1 = *(const float4*)(Wo + (mt * 16 + l15) * 32 + 16 + l4 * 4);
        wA[mt][0] = cvt4(w0);
        wA[mt][1] = cvt4(w1);
    }
    const float gamma = *gammap;

    // --- staging addresses (per thread)
    // phi: thread t loads 8 B: row = t>>1 (0..127), half = t&1
    const unsigned short* phSrc = phiT + ((size_t)b * M_ + (tid >> 1)) * 8 + (tid & 1) * 4;
    const int phOff = (tid >> 1) * 8 + (tid & 1) * 4;
    // g: thread t: ch = t>>3, keys (t&7)*16 .. +15 (32 B = 2 uint4)
    const int gch = tid >> 3, gseg = (tid & 7) * 16;
    const unsigned short* gSrc = gcm + ((size_t)(b * 32 + gch)) * M_ + gseg;
    const int gOff = gch * G2_STR + gseg;

    // --- prologue: load + write tile 0
    uint2 r_ph = *(const uint2*)phSrc;
    uint4 r_g0 = *(const uint4*)(gSrc + 0);
    uint4 r_g1 = *(const uint4*)(gSrc + 8);
    *(uint2*)&phiL[phOff] = r_ph;
    *(uint4*)&gL[gOff + 0] = r_g0;
    *(uint4*)&gL[gOff + 8] = r_g1;
    __syncthreads();

    v4f acc0, acc1;
    { v4f z = {}; acc0 = z; acc1 = z; }
    float lsum = 0.f;
    const v4f zf = {};

    for (int t = 0; t < 8; ++t) {            // 8 key tiles of 128
        const unsigned short* Pb = &phiL[(t & 1) * P2_SZ];
        const unsigned short* Gb = &gL[(t & 1) * G2_SZ];
        // issue next tile's global loads BEFORE compute (latency hides here)
        if (t < 7) {
            r_ph = *(const uint2*)(phSrc + (size_t)(t + 1) * 128 * 8);
            r_g0 = *(const uint4*)(gSrc + (t + 1) * 128 + 0);
            r_g1 = *(const uint4*)(gSrc + (t + 1) * 128 + 8);
        }
        // compute 8 chunks of 16 keys from LDS
        const unsigned short* pAddr = Pb + l15 * 8 + (l4 & 1) * 4;  // dup for l4>=2 (B=0 there)
        const unsigned short* gAddr = Gb + l15 * G2_STR + l4 * 4;
        #pragma unroll
        for (int kk = 0; kk < 8; ++kk) {
            const v4s aph = *(const v4s*)(pAddr + kk * 128);
            const v4s ag0 = *(const v4s*)(gAddr + kk * 16);
            const v4s ag1 = *(const v4s*)(gAddr + 16 * G2_STR + kk * 16);
            v4f s = mfma16(aph, bth, zf);
            const float e0 = __expf(s[0]), e1 = __expf(s[1]);
            const float e2 = __expf(s[2]), e3 = __expf(s[3]);
            lsum += (e0 + e1) + (e2 + e3);
            union { v4s v; unsigned u[2]; } p;
            p.u[0] = pack2bf(e0, e1);
            p.u[1] = pack2bf(e2, e3);
            acc0 = mfma16(ag0, p.v, acc0);
            acc1 = mfma16(ag1, p.v, acc1);
        }
        // write-late: next tile into the other buffer, one barrier per tile
        if (t < 7) {
            unsigned short* Pn = &phiL[((t + 1) & 1) * P2_SZ];
            unsigned short* Gn = &gL[((t + 1) & 1) * G2_SZ];
            *(uint2*)&Pn[phOff] = r_ph;
            *(uint4*)&Gn[gOff + 0] = r_g0;
            *(uint4*)&Gn[gOff + 8] = r_g1;
            __syncthreads();
        }
    }

    // --- softmax denominator: sum over the 4 l4-groups sharing query l15
    float v = lsum;
    v += __shfl_xor(v, 16);
    v += __shfl_xor(v, 32);
    const float rl = 1.0f / v;

    // --- normalize + pack O -> B-frags of the output-conv MFMA (k=c=l4*4+j)
    v4s pO0, pO1;
    {
        union { v4s v; unsigned u[2]; } p;
        p.u[0] = pack2bf(acc0[0] * rl, acc0[1] * rl);
        p.u[1] = pack2bf(acc0[2] * rl, acc0[3] * rl);
        pO0 = p.v;
        p.u[0] = pack2bf(acc1[0] * rl, acc1[1] * rl);
        p.u[1] = pack2bf(acc1[2] * rl, acc1[3] * rl);
        pO1 = p.v;
    }

    // --- output conv via 8 K=16 MFMAs + residual.  D[m=oc][n=q], bias in C.
    const size_t colq = qw + l15;
    #pragma unroll
    for (int mt = 0; mt < 4; ++mt) {
        const int oc0 = mt * 16 + l4 * 4;
        const float4 bo4 = *(const float4*)(bo + oc0);
        v4f c; c[0] = bo4.x; c[1] = bo4.y; c[2] = bo4.z; c[3] = bo4.w;
        c = mfma16(wA[mt][0], pO0, c);
        c = mfma16(wA[mt][1], pO1, c);
        const float* xr   = x   + ((size_t)(b * 64 + oc0)) * N_ + colq;
        float*       orow = out + ((size_t)(b * 64 + oc0)) * N_ + colq;
        #pragma unroll
        for (int r = 0; r < 4; ++r)
            orow[(size_t)r * N_] = gamma * c[r] + xr[(size_t)r * N_];
    }
}

// ---------------------------------------------------------------------------
extern "C" void kernel_launch(void* const* d_in, const int* in_sizes, int n_in,
                              void* d_out, int out_size, void* d_ws, size_t ws_size,
                              hipStream_t stream) {
    const float* x  = (const float*)d_in[0];
    const float* Wt = (const float*)d_in[1];
    const float* bt = (const float*)d_in[2];
    const float* Wp = (const float*)d_in[3];
    const float* bp = (const float*)d_in[4];
    const float* Wg = (const float*)d_in[5];
    const float* bg = (const float*)d_in[6];
    const float* Wo = (const float*)d_in[7];
    const float* bo = (const float*)d_in[8];
    const float* gm = (const float*)d_in[9];
    float* out = (float*)d_out;

    // workspace (bf16): thetaT [16][4096][8] | phiT [16][1024][8] | gcm [16][32][1024]
    unsigned short* thetaT = (unsigned short*)d_ws;
    unsigned short* phiT   = thetaT + (size_t)B_ * N_ * 8;
    unsigned short* gcm    = phiT   + (size_t)B_ * M_ * 8;

    hipLaunchKernelGGL(conv_pool_k, dim3(512), dim3(256), 0, stream,
                       x, Wt, bt, Wp, bp, Wg, bg, thetaT, phiT, gcm);
    hipLaunchKernelGGL(attn_k, dim3(1024), dim3(256), 0, stream,
                       x, thetaT, phiT, gcm, Wo, bo, gm, out);
}